// Round 9
// baseline (178.012 us; speedup 1.0000x reference)
//
#include <hip/hip_runtime.h>

#define CIN   32
#define COUT  64
#define K_OFF 27

typedef __attribute__((ext_vector_type(8))) short bf16x8;
typedef __attribute__((ext_vector_type(4))) float f32x4;

// exact vmcnt fence + compiler memory pin (defines VMEM issue order)
#define FENCE_VM(N) asm volatile("s_waitcnt vmcnt(" #N ")" ::: "memory")
#define PIN()       asm volatile("" ::: "memory")

__device__ inline unsigned short f2bf_rne(float f) {
    union { float f; unsigned int u; } v; v.f = f;
    unsigned int u = v.u;
    u = (u + 0x7fffu + ((u >> 16) & 1u)) >> 16;
    return (unsigned short)u;
}

// async 16B global -> LDS (per-lane src addr; LDS dest = wave-uniform base
// + lane*16). Completion signaled via vmcnt (NOT lgkm) — hence FENCE_VM.
__device__ inline void async_load16(const void* g, void* l) {
    __builtin_amdgcn_global_load_lds(
        (const __attribute__((address_space(1))) void*)g,
        (__attribute__((address_space(3))) void*)l, 16, 0, 0);
}

// ---------------------------------------------------------------------------
// Mask-dtype detect (4KB scan) + zero the 64B zero-row in ws (ws re-poisoned
// 0xAA before every call, so this must run every call).
// ---------------------------------------------------------------------------
__global__ __launch_bounds__(256) void detect_mask(
    const unsigned char* __restrict__ mask, int nbytes, int* __restrict__ flag,
    float* __restrict__ zrow) {
    __shared__ int wany[4];
    int found = 0;
    for (int i = threadIdx.x; i < nbytes; i += 256)
        if ((i & 3) && mask[i]) found = 1;
    unsigned long long b = __ballot(found);
    if ((threadIdx.x & 63) == 0) wany[threadIdx.x >> 6] = b ? 1 : 0;
    __syncthreads();
    if (threadIdx.x == 0) *flag = wany[0] | wany[1] | wany[2] | wany[3];
    if (threadIdx.x < 16) zrow[threadIdx.x] = 0.0f;
}

// ---------------------------------------------------------------------------
// Fused prep:
//   [0,Bf)        feat fp32 -> bf16
//   [Bf,Bf+Bm)    midx = mask ? nmap : -1
//   [Bf+Bm,..)    weights -> fragment-order bf16 wt2[k][ct][lane][8]
// ---------------------------------------------------------------------------
__global__ __launch_bounds__(256) void prep_kernel(
    const float* __restrict__ feat, const int* __restrict__ nmap,
    const unsigned char* __restrict__ mask8, const int* __restrict__ mask32,
    const float* __restrict__ wk,
    unsigned short* __restrict__ featb, int* __restrict__ midx,
    unsigned short* __restrict__ wt2,
    int n, int Bf, int Bm, const int* __restrict__ flag)
{
    const int gid = blockIdx.x;
    if (gid < Bf) {
        const int base = (gid * 256 + threadIdx.x) * 8;
        if (base < n * CIN) {
            float4 a = *(const float4*)(feat + base);
            float4 b = *(const float4*)(feat + base + 4);
            bf16x8 v;
            v[0] = (short)f2bf_rne(a.x); v[1] = (short)f2bf_rne(a.y);
            v[2] = (short)f2bf_rne(a.z); v[3] = (short)f2bf_rne(a.w);
            v[4] = (short)f2bf_rne(b.x); v[5] = (short)f2bf_rne(b.y);
            v[6] = (short)f2bf_rne(b.z); v[7] = (short)f2bf_rne(b.w);
            *(bf16x8*)(featb + base) = v;
        }
    } else if (gid < Bf + Bm) {
        const int t = (gid - Bf) * 256 + threadIdx.x;
        int i = t * 4;
        const int total = K_OFF * n;
        const int is_b8 = *flag;
        if (i + 3 < total) {
            int4 nm = *(const int4*)(nmap + i);
            int m0, m1, m2, m3;
            if (is_b8) {
                uchar4 mb = *(const uchar4*)(mask8 + i);
                m0 = mb.x; m1 = mb.y; m2 = mb.z; m3 = mb.w;
            } else {
                int4 mm = *(const int4*)(mask32 + i);
                m0 = mm.x; m1 = mm.y; m2 = mm.z; m3 = mm.w;
            }
            int4 r;
            r.x = m0 ? nm.x : -1; r.y = m1 ? nm.y : -1;
            r.z = m2 ? nm.z : -1; r.w = m3 ? nm.w : -1;
            *(int4*)(midx + i) = r;
        } else {
            for (; i < total; ++i) {
                int m = is_b8 ? (int)mask8[i] : mask32[i];
                midx[i] = m ? nmap[i] : -1;
            }
        }
    } else {
        const int t = (gid - Bf - Bm) * 256 + threadIdx.x;  // fragment id
        if (t < K_OFF * 4 * 64) {
            const int lane = t & 63, ct = (t >> 6) & 3, k = t >> 8;
            const int lrow = lane & 15, q = lane >> 4;
            const int col = ct * 16 + lrow;
            bf16x8 v;
            #pragma unroll
            for (int j = 0; j < 8; ++j)
                v[j] = (short)f2bf_rne(wk[(k * CIN + q * 8 + j) * COUT + col]);
            *(bf16x8*)(wt2 + t * 8) = v;
        }
    }
}

// ---------------------------------------------------------------------------
// Main MFMA kernel — DMA-ring pipeline with EXPLICIT vmcnt fences (R8 fix:
// global_load_lds completes on vmcnt; the compiler does not connect that to
// the consuming ds_read, so we fence by hand; PIN() makes VMEM issue order
// source-defined so each fence's count is exact — never vmcnt(0), younger
// prefetches stay in flight, AITER-style).
// Ring: 4 LDS slots (32KB/block), DMA issued at iter k for slot k+3 and
// consumed at iter k (depth 3). midx prefetched +4 (reg, 2 slots), B +1.
// Barrier-free; wave = 32 rows x 64 couts, 8 MFMA/iter. Masked lanes DMA
// from a 64B zero row so LDS is never stale.
// ---------------------------------------------------------------------------
__global__ __launch_bounds__(256) void conv_mfma9(
    const unsigned short* __restrict__ featb,   // [N][CIN] bf16
    const int*            __restrict__ midx,    // [K][N] fused mask?nmap:-1
    const unsigned short* __restrict__ wt2,     // fragment-order weights
    const unsigned short* __restrict__ zrow,    // 64B of zeros
    float* __restrict__ out, int n)
{
    __shared__ __attribute__((aligned(16))) unsigned short As0[4][2][512];
    __shared__ __attribute__((aligned(16))) unsigned short As1[4][2][512];
    __shared__ __attribute__((aligned(16))) unsigned short As2[4][2][512];
    __shared__ __attribute__((aligned(16))) unsigned short As3[4][2][512];

    const int tid  = threadIdx.x;
    const int wave = tid >> 6;
    const int lane = tid & 63;
    const int lrow = lane & 15;
    const int q    = lane >> 4;
    const int n0   = blockIdx.x * 128 + wave * 32;

    const int  row0 = n0 + lrow, row1 = n0 + 16 + lrow;
    const bool vr0 = row0 < n, vr1 = row1 < n;

    auto load_mi = [&](int k, int rt) -> int {
        const int  r = rt ? row1 : row0;
        const bool v = rt ? vr1 : vr0;
        if (!v) return -1;
        return midx[k * n + r];
    };
    auto slotp = [&](int s, int rt) -> unsigned short* {
        return s == 0 ? &As0[wave][rt][0]
             : s == 1 ? &As1[wave][rt][0]
             : s == 2 ? &As2[wave][rt][0]
                      : &As3[wave][rt][0];
    };
    auto issue_gather = [&](int mi, unsigned short* ldsbase) {
        const unsigned short* src =
            (mi >= 0) ? featb + (size_t)mi * CIN + q * 8 : zrow;
        async_load16(src, ldsbase);
    };
    auto loadB = [&](int k, bf16x8* dst) {
        const unsigned short* p = wt2 + ((k * 4) << 9) + lane * 8;
        #pragma unroll
        for (int ct = 0; ct < 4; ++ct) dst[ct] = *(const bf16x8*)(p + (ct << 9));
    };

    int    mi_buf[2][2];
    bf16x8 B_buf[2][4];
    f32x4  acc[2][4] = {};

    // prologue (pinned groups): midx temps k=0..2 + midx[3]; DMA slots 0..2;
    // B[0]. Fence counts below assume exactly this issue order.
    {
        int p00 = load_mi(0, 0), p01 = load_mi(0, 1);
        int p10 = load_mi(1, 0), p11 = load_mi(1, 1);
        int p20 = load_mi(2, 0), p21 = load_mi(2, 1);
        mi_buf[1][0] = load_mi(3, 0);     // slot (0+1)&1, consumed at k=0
        mi_buf[1][1] = load_mi(3, 1);
        PIN();
        issue_gather(p00, slotp(0, 0)); issue_gather(p01, slotp(0, 1));
        PIN();
        issue_gather(p10, slotp(1, 0)); issue_gather(p11, slotp(1, 1));
        PIN();
        issue_gather(p20, slotp(2, 0)); issue_gather(p21, slotp(2, 1));
        PIN();
        loadB(0, B_buf[0]);
        PIN();
    }

    #pragma unroll
    for (int k = 0; k < K_OFF; ++k) {
        // wait for slot-k DMA (issued 3 bodies ago); exact younger-VMEM counts
        if      (k == 0)  FENCE_VM(8);
        else if (k == 1)  FENCE_VM(14);
        else if (k <= 23) FENCE_VM(20);
        else if (k == 24) FENCE_VM(18);
        else if (k == 25) FENCE_VM(14);
        else              FENCE_VM(12);

        bf16x8 a0 = *(const bf16x8*)(slotp(k & 3, 0) + lane * 8);
        bf16x8 a1 = *(const bf16x8*)(slotp(k & 3, 1) + lane * 8);

        if (k + 4 < K_OFF) {                  // midx[k+4] -> mi slot k&1
            mi_buf[k & 1][0] = load_mi(k + 4, 0);
            mi_buf[k & 1][1] = load_mi(k + 4, 1);
        }
        PIN();
        if (k + 3 < K_OFF) {                  // DMA k+3 (midx from slot (k+1)&1)
            issue_gather(mi_buf[(k + 1) & 1][0], slotp((k + 3) & 3, 0));
            issue_gather(mi_buf[(k + 1) & 1][1], slotp((k + 3) & 3, 1));
        }
        PIN();
        if (k + 1 < K_OFF) loadB(k + 1, B_buf[(k + 1) & 1]);
        PIN();

        const int bs = k & 1;
        #pragma unroll
        for (int ct = 0; ct < 4; ++ct) {
            acc[0][ct] = __builtin_amdgcn_mfma_f32_16x16x32_bf16(
                a0, B_buf[bs][ct], acc[0][ct], 0, 0, 0);
            acc[1][ct] = __builtin_amdgcn_mfma_f32_16x16x32_bf16(
                a1, B_buf[bs][ct], acc[1][ct], 0, 0, 0);
        }
    }

    // epilogue: C/D layout col=lane&15, row=q*4+reg
    #pragma unroll
    for (int rt = 0; rt < 2; ++rt)
        #pragma unroll
        for (int ct = 0; ct < 4; ++ct)
            #pragma unroll
            for (int r = 0; r < 4; ++r) {
                const int row = n0 + rt * 16 + q * 4 + r;
                if (row < n) out[(size_t)row * COUT + ct * 16 + lrow] = acc[rt][ct][r];
            }
}

// ---------------------------------------------------------------------------
// fp32 fallback path (only if ws too small for bf16 staging).
// ---------------------------------------------------------------------------
#define BN 64
__global__ __launch_bounds__(256) void sparse_conv_fp32(
    const float* __restrict__ feat, const int* __restrict__ nmap,
    const unsigned char* __restrict__ mask8, const int* __restrict__ mask32,
    const float* __restrict__ wk, float* __restrict__ out,
    int n, const int* __restrict__ flag)
{
    __shared__ float A[CIN][BN];
    __shared__ float W[CIN][COUT];
    const int tid = threadIdx.x;
    const int n0 = blockIdx.x * BN;
    const int is_b8 = *flag;
    const int r0 = (tid >> 4) * 4, c0 = (tid & 15) * 4;
    const int grow = tid >> 2, gpart = tid & 3;
    float acc[4][4] = {};
    for (int k = 0; k < K_OFF; ++k) {
        {
            const int base = tid * 8;
            const float* wsrc = wk + (size_t)k * (CIN * COUT) + base;
            float4 w0 = ((const float4*)wsrc)[0];
            float4 w1 = ((const float4*)wsrc)[1];
            *(float4*)&W[base >> 6][base & 63] = w0;
            *(float4*)&W[base >> 6][(base & 63) + 4] = w1;
        }
        {
            const int gn = n0 + grow;
            float4 f0 = make_float4(0.f, 0.f, 0.f, 0.f), f1 = f0;
            if (gn < n) {
                const int idx = k * n + gn;
                const int m = is_b8 ? (int)mask8[idx] : mask32[idx];
                if (m) {
                    const float* fsrc = feat + (size_t)nmap[idx] * CIN + gpart * 8;
                    f0 = ((const float4*)fsrc)[0];
                    f1 = ((const float4*)fsrc)[1];
                }
            }
            const int cb = gpart * 8;
            A[cb+0][grow]=f0.x; A[cb+1][grow]=f0.y; A[cb+2][grow]=f0.z; A[cb+3][grow]=f0.w;
            A[cb+4][grow]=f1.x; A[cb+5][grow]=f1.y; A[cb+6][grow]=f1.z; A[cb+7][grow]=f1.w;
        }
        __syncthreads();
        #pragma unroll
        for (int c = 0; c < CIN; ++c) {
            const float4 a = *(const float4*)&A[c][r0];
            const float4 w = *(const float4*)&W[c][c0];
            acc[0][0]+=a.x*w.x; acc[0][1]+=a.x*w.y; acc[0][2]+=a.x*w.z; acc[0][3]+=a.x*w.w;
            acc[1][0]+=a.y*w.x; acc[1][1]+=a.y*w.y; acc[1][2]+=a.y*w.z; acc[1][3]+=a.y*w.w;
            acc[2][0]+=a.z*w.x; acc[2][1]+=a.z*w.y; acc[2][2]+=a.z*w.z; acc[2][3]+=a.z*w.w;
            acc[3][0]+=a.w*w.x; acc[3][1]+=a.w*w.y; acc[3][2]+=a.w*w.z; acc[3][3]+=a.w*w.w;
        }
        __syncthreads();
    }
    #pragma unroll
    for (int i = 0; i < 4; ++i) {
        const int orow = n0 + r0 + i;
        if (orow < n)
            *(float4*)&out[(size_t)orow * COUT + c0] =
                make_float4(acc[i][0], acc[i][1], acc[i][2], acc[i][3]);
    }
}

static inline size_t align16(size_t x) { return (x + 15) & ~(size_t)15; }

extern "C" void kernel_launch(void* const* d_in, const int* in_sizes, int n_in,
                              void* d_out, int out_size, void* d_ws, size_t ws_size,
                              hipStream_t stream) {
    const float*         feat = (const float*)d_in[0];
    const int*           nmap = (const int*)d_in[1];
    const unsigned char* m8   = (const unsigned char*)d_in[2];
    const int*           m32  = (const int*)d_in[2];
    const float*         wk   = (const float*)d_in[3];
    float*               out  = (float*)d_out;

    const int n = in_sizes[0] / CIN;
    int* flag = (int*)d_ws;
    float* zrow = (float*)((char*)d_ws + 64);       // 64B zero row

    const size_t feat_off   = 128;
    const size_t feat_bytes = (size_t)n * CIN * 2;
    const size_t midx_off   = align16(feat_off + feat_bytes);
    const size_t midx_bytes = (size_t)K_OFF * n * 4;
    const size_t wt2_off    = align16(midx_off + midx_bytes);
    const size_t wt2_bytes  = (size_t)K_OFF * 4 * 64 * 8 * 2;
    const size_t needed     = wt2_off + wt2_bytes;

    const int mask_elems = K_OFF * n;
    const int det_bytes  = mask_elems < 4096 ? mask_elems : 4096;
    detect_mask<<<1, 256, 0, stream>>>(m8, det_bytes, flag, zrow);

    if (ws_size >= needed) {
        unsigned short* featb = (unsigned short*)((char*)d_ws + feat_off);
        int*            midx  = (int*)((char*)d_ws + midx_off);
        unsigned short* wt2   = (unsigned short*)((char*)d_ws + wt2_off);
        const int Bf = (n * CIN / 8 + 255) / 256;
        const int Bm = ((K_OFF * n + 3) / 4 + 255) / 256;
        const int Bw = (K_OFF * 4 * 64 + 255) / 256;
        prep_kernel<<<Bf + Bm + Bw, 256, 0, stream>>>(
            feat, nmap, m8, m32, wk, featb, midx, wt2, n, Bf, Bm, flag);
        const int nblocks = (n + 127) / 128;
        conv_mfma9<<<nblocks, 256, 0, stream>>>(
            featb, midx, wt2, (const unsigned short*)zrow, out, n);
    } else {
        const int nb = (n + BN - 1) / BN;
        sparse_conv_fp32<<<nb, 256, 0, stream>>>(feat, nmap, m8, m32, wk, out, n, flag);
    }
}

// Round 10
// 169.881 us; speedup vs baseline: 1.0479x; 1.0479x over previous
//
#include <hip/hip_runtime.h>

#define CIN   32
#define COUT  64
#define K_OFF 27

typedef __attribute__((ext_vector_type(8))) short bf16x8;
typedef __attribute__((ext_vector_type(4))) float f32x4;

// exact vmcnt fence + compiler memory pin (defines VMEM issue order)
#define FENCE_VM(N) asm volatile("s_waitcnt vmcnt(" #N ")" ::: "memory")
#define PIN()       asm volatile("" ::: "memory")
#define BARRIER()   asm volatile("s_barrier" ::: "memory")

__device__ inline unsigned short f2bf_rne(float f) {
    union { float f; unsigned int u; } v; v.f = f;
    unsigned int u = v.u;
    u = (u + 0x7fffu + ((u >> 16) & 1u)) >> 16;
    return (unsigned short)u;
}

// async 16B global -> LDS (per-lane src addr; LDS dest = wave-uniform base
// + lane*16). Completion signaled via vmcnt — fenced by hand (R8/R9 lesson).
__device__ inline void async_load16(const void* g, void* l) {
    __builtin_amdgcn_global_load_lds(
        (const __attribute__((address_space(1))) void*)g,
        (__attribute__((address_space(3))) void*)l, 16, 0, 0);
}

// ---------------------------------------------------------------------------
// Mask-dtype detect (4KB scan) + zero the 64B zero-row in ws (ws re-poisoned
// 0xAA before every call).
// ---------------------------------------------------------------------------
__global__ __launch_bounds__(256) void detect_mask(
    const unsigned char* __restrict__ mask, int nbytes, int* __restrict__ flag,
    float* __restrict__ zrow) {
    __shared__ int wany[4];
    int found = 0;
    for (int i = threadIdx.x; i < nbytes; i += 256)
        if ((i & 3) && mask[i]) found = 1;
    unsigned long long b = __ballot(found);
    if ((threadIdx.x & 63) == 0) wany[threadIdx.x >> 6] = b ? 1 : 0;
    __syncthreads();
    if (threadIdx.x == 0) *flag = wany[0] | wany[1] | wany[2] | wany[3];
    if (threadIdx.x < 16) zrow[threadIdx.x] = 0.0f;
}

// ---------------------------------------------------------------------------
// Fused prep:
//   [0,Bf)        feat fp32 -> bf16
//   [Bf,Bf+Bm)    midx = mask ? nmap : -1
//   [Bf+Bm,..)    weights -> fragment-order bf16 wt2[k][ct][lane][8]
// ---------------------------------------------------------------------------
__global__ __launch_bounds__(256) void prep_kernel(
    const float* __restrict__ feat, const int* __restrict__ nmap,
    const unsigned char* __restrict__ mask8, const int* __restrict__ mask32,
    const float* __restrict__ wk,
    unsigned short* __restrict__ featb, int* __restrict__ midx,
    unsigned short* __restrict__ wt2,
    int n, int Bf, int Bm, const int* __restrict__ flag)
{
    const int gid = blockIdx.x;
    if (gid < Bf) {
        const int base = (gid * 256 + threadIdx.x) * 8;
        if (base < n * CIN) {
            float4 a = *(const float4*)(feat + base);
            float4 b = *(const float4*)(feat + base + 4);
            bf16x8 v;
            v[0] = (short)f2bf_rne(a.x); v[1] = (short)f2bf_rne(a.y);
            v[2] = (short)f2bf_rne(a.z); v[3] = (short)f2bf_rne(a.w);
            v[4] = (short)f2bf_rne(b.x); v[5] = (short)f2bf_rne(b.y);
            v[6] = (short)f2bf_rne(b.z); v[7] = (short)f2bf_rne(b.w);
            *(bf16x8*)(featb + base) = v;
        }
    } else if (gid < Bf + Bm) {
        const int t = (gid - Bf) * 256 + threadIdx.x;
        int i = t * 4;
        const int total = K_OFF * n;
        const int is_b8 = *flag;
        if (i + 3 < total) {
            int4 nm = *(const int4*)(nmap + i);
            int m0, m1, m2, m3;
            if (is_b8) {
                uchar4 mb = *(const uchar4*)(mask8 + i);
                m0 = mb.x; m1 = mb.y; m2 = mb.z; m3 = mb.w;
            } else {
                int4 mm = *(const int4*)(mask32 + i);
                m0 = mm.x; m1 = mm.y; m2 = mm.z; m3 = mm.w;
            }
            int4 r;
            r.x = m0 ? nm.x : -1; r.y = m1 ? nm.y : -1;
            r.z = m2 ? nm.z : -1; r.w = m3 ? nm.w : -1;
            *(int4*)(midx + i) = r;
        } else {
            for (; i < total; ++i) {
                int m = is_b8 ? (int)mask8[i] : mask32[i];
                midx[i] = m ? nmap[i] : -1;
            }
        }
    } else {
        const int t = (gid - Bf - Bm) * 256 + threadIdx.x;  // fragment id
        if (t < K_OFF * 4 * 64) {
            const int lane = t & 63, ct = (t >> 6) & 3, k = t >> 8;
            const int lrow = lane & 15, q = lane >> 4;
            const int col = ct * 16 + lrow;
            bf16x8 v;
            #pragma unroll
            for (int j = 0; j < 8; ++j)
                v[j] = (short)f2bf_rne(wk[(k * CIN + q * 8 + j) * COUT + col]);
            *(bf16x8*)(wt2 + t * 8) = v;
        }
    }
}

// ---------------------------------------------------------------------------
// Main MFMA kernel — R9's fenced DMA-ring, plus BLOCK-SHARED B staging:
// R9's counters showed TA-throughput-bound (~100 lookup-cyc/body/wave),
// 64 of which were per-wave B-frag loads of the SAME 4KB slice. Now each
// wave DMAs only its ct-quarter (1KB) of B into a tri-buffered LDS slot;
// all 4 waves read frags via ds_read_b128 (LDS pipe is idle). Cross-wave
// visibility: each wave fences its OWN DMA (exact vmcnt) then raw
// s_barrier (asm — compiler never sees a __syncthreads, so no vmcnt(0)
// drain; gather prefetches stay in flight across the barrier).
// Per-body VMEM (pinned order): [B(k+2)] [G(k+2)x2] [M(k+4)x2].
// Fences (end of body k): exact younger-count for B(k+1),G(k+1):
//   k=0:5, 1..22:7, 23:5, 24:3, 25:0, 26:none.
// A-ring 3 slots/wave (24KB) + B 3 slots (12KB) = 36KB LDS/block.
// Wave = 32 rows x 64 couts, 8 MFMA/body. Masked lanes DMA a zero row.
// ---------------------------------------------------------------------------
__global__ __launch_bounds__(256) void conv_mfma10(
    const unsigned short* __restrict__ featb,   // [N][CIN] bf16
    const int*            __restrict__ midx,    // [K][N] fused mask?nmap:-1
    const unsigned short* __restrict__ wt2,     // fragment-order weights
    const unsigned short* __restrict__ zrow,    // 64B of zeros
    float* __restrict__ out, int n)
{
    __shared__ __attribute__((aligned(16))) unsigned short Bs[3][4][512];    // 12 KB
    __shared__ __attribute__((aligned(16))) unsigned short As[3][4][2][512]; // 24 KB

    const int tid  = threadIdx.x;
    const int wave = tid >> 6;
    const int lane = tid & 63;
    const int lrow = lane & 15;
    const int q    = lane >> 4;
    const int n0   = blockIdx.x * 128 + wave * 32;

    const int  row0 = n0 + lrow, row1 = n0 + 16 + lrow;
    const bool vr0 = row0 < n, vr1 = row1 < n;

    auto load_mi = [&](int k, int rt) -> int {
        const int  r = rt ? row1 : row0;
        const bool v = rt ? vr1 : vr0;
        if (!v) return -1;
        return midx[k * n + r];
    };
    auto issue_gather = [&](int mi, unsigned short* ldsbase) {
        const unsigned short* src =
            (mi >= 0) ? featb + (size_t)mi * CIN + q * 8 : zrow;
        async_load16(src, ldsbase);
    };
    auto stageB = [&](int k) {   // this wave's ct-quarter of slice k
        const unsigned short* src = wt2 + (((k * 4 + wave)) << 9) + lane * 8;
        async_load16(src, &Bs[k % 3][wave][0]);
    };

    int   mi_buf[2][2];
    f32x4 acc[2][4] = {};

    // ---- prologue: M(0..3); B(0),B(1); G(0),G(1). Fence leaves G(1) in flight.
    {
        int p00 = load_mi(0, 0), p01 = load_mi(0, 1);
        int p10 = load_mi(1, 0), p11 = load_mi(1, 1);
        mi_buf[0][0] = load_mi(2, 0); mi_buf[0][1] = load_mi(2, 1);
        mi_buf[1][0] = load_mi(3, 0); mi_buf[1][1] = load_mi(3, 1);
        PIN();
        stageB(0);
        stageB(1);
        PIN();
        issue_gather(p00, &As[0][wave][0][0]);
        issue_gather(p01, &As[0][wave][1][0]);
        PIN();
        issue_gather(p10, &As[1][wave][0][0]);
        issue_gather(p11, &As[1][wave][1][0]);
        PIN();
        FENCE_VM(2);    // B0,B1,G0x2 complete; G1x2 in flight
        BARRIER();
    }

    #pragma unroll
    for (int k = 0; k < K_OFF; ++k) {
        // ---- consume LDS (fenced+barriered at end of previous body)
        bf16x8 a0 = *(const bf16x8*)(&As[k % 3][wave][0][lane * 8]);
        bf16x8 a1 = *(const bf16x8*)(&As[k % 3][wave][1][lane * 8]);
        bf16x8 b0 = *(const bf16x8*)(&Bs[k % 3][0][lane * 8]);
        bf16x8 b1 = *(const bf16x8*)(&Bs[k % 3][1][lane * 8]);
        bf16x8 b2 = *(const bf16x8*)(&Bs[k % 3][2][lane * 8]);
        bf16x8 b3 = *(const bf16x8*)(&Bs[k % 3][3][lane * 8]);
        PIN();

        // ---- prefetch issues (pinned order: B, G, M)
        if (k + 2 < K_OFF) {
            stageB(k + 2);
            PIN();
            issue_gather(mi_buf[k & 1][0], &As[(k + 2) % 3][wave][0][0]);
            issue_gather(mi_buf[k & 1][1], &As[(k + 2) % 3][wave][1][0]);
            PIN();
        }
        if (k + 4 < K_OFF) {
            mi_buf[k & 1][0] = load_mi(k + 4, 0);
            mi_buf[k & 1][1] = load_mi(k + 4, 1);
            PIN();
        }

        // ---- 8 MFMA
        acc[0][0] = __builtin_amdgcn_mfma_f32_16x16x32_bf16(a0, b0, acc[0][0], 0, 0, 0);
        acc[1][0] = __builtin_amdgcn_mfma_f32_16x16x32_bf16(a1, b0, acc[1][0], 0, 0, 0);
        acc[0][1] = __builtin_amdgcn_mfma_f32_16x16x32_bf16(a0, b1, acc[0][1], 0, 0, 0);
        acc[1][1] = __builtin_amdgcn_mfma_f32_16x16x32_bf16(a1, b1, acc[1][1], 0, 0, 0);
        acc[0][2] = __builtin_amdgcn_mfma_f32_16x16x32_bf16(a0, b2, acc[0][2], 0, 0, 0);
        acc[1][2] = __builtin_amdgcn_mfma_f32_16x16x32_bf16(a1, b2, acc[1][2], 0, 0, 0);
        acc[0][3] = __builtin_amdgcn_mfma_f32_16x16x32_bf16(a0, b3, acc[0][3], 0, 0, 0);
        acc[1][3] = __builtin_amdgcn_mfma_f32_16x16x32_bf16(a1, b3, acc[1][3], 0, 0, 0);

        // ---- fence own next-body prefetch, then block barrier
        if (k < K_OFF - 1) {
            if      (k == 0)  FENCE_VM(5);
            else if (k <= 22) FENCE_VM(7);
            else if (k == 23) FENCE_VM(5);
            else if (k == 24) FENCE_VM(3);
            else              FENCE_VM(0);
            BARRIER();
        }
    }

    // epilogue: C/D layout col=lane&15, row=q*4+reg
    #pragma unroll
    for (int rt = 0; rt < 2; ++rt)
        #pragma unroll
        for (int ct = 0; ct < 4; ++ct)
            #pragma unroll
            for (int r = 0; r < 4; ++r) {
                const int row = n0 + rt * 16 + q * 4 + r;
                if (row < n) out[(size_t)row * COUT + ct * 16 + lrow] = acc[rt][ct][r];
            }
}

// ---------------------------------------------------------------------------
// fp32 fallback path (only if ws too small for bf16 staging).
// ---------------------------------------------------------------------------
#define BN 64
__global__ __launch_bounds__(256) void sparse_conv_fp32(
    const float* __restrict__ feat, const int* __restrict__ nmap,
    const unsigned char* __restrict__ mask8, const int* __restrict__ mask32,
    const float* __restrict__ wk, float* __restrict__ out,
    int n, const int* __restrict__ flag)
{
    __shared__ float A[CIN][BN];
    __shared__ float W[CIN][COUT];
    const int tid = threadIdx.x;
    const int n0 = blockIdx.x * BN;
    const int is_b8 = *flag;
    const int r0 = (tid >> 4) * 4, c0 = (tid & 15) * 4;
    const int grow = tid >> 2, gpart = tid & 3;
    float acc[4][4] = {};
    for (int k = 0; k < K_OFF; ++k) {
        {
            const int base = tid * 8;
            const float* wsrc = wk + (size_t)k * (CIN * COUT) + base;
            float4 w0 = ((const float4*)wsrc)[0];
            float4 w1 = ((const float4*)wsrc)[1];
            *(float4*)&W[base >> 6][base & 63] = w0;
            *(float4*)&W[base >> 6][(base & 63) + 4] = w1;
        }
        {
            const int gn = n0 + grow;
            float4 f0 = make_float4(0.f, 0.f, 0.f, 0.f), f1 = f0;
            if (gn < n) {
                const int idx = k * n + gn;
                const int m = is_b8 ? (int)mask8[idx] : mask32[idx];
                if (m) {
                    const float* fsrc = feat + (size_t)nmap[idx] * CIN + gpart * 8;
                    f0 = ((const float4*)fsrc)[0];
                    f1 = ((const float4*)fsrc)[1];
                }
            }
            const int cb = gpart * 8;
            A[cb+0][grow]=f0.x; A[cb+1][grow]=f0.y; A[cb+2][grow]=f0.z; A[cb+3][grow]=f0.w;
            A[cb+4][grow]=f1.x; A[cb+5][grow]=f1.y; A[cb+6][grow]=f1.z; A[cb+7][grow]=f1.w;
        }
        __syncthreads();
        #pragma unroll
        for (int c = 0; c < CIN; ++c) {
            const float4 a = *(const float4*)&A[c][r0];
            const float4 w = *(const float4*)&W[c][c0];
            acc[0][0]+=a.x*w.x; acc[0][1]+=a.x*w.y; acc[0][2]+=a.x*w.z; acc[0][3]+=a.x*w.w;
            acc[1][0]+=a.y*w.x; acc[1][1]+=a.y*w.y; acc[1][2]+=a.y*w.z; acc[1][3]+=a.y*w.w;
            acc[2][0]+=a.z*w.x; acc[2][1]+=a.z*w.y; acc[2][2]+=a.z*w.z; acc[2][3]+=a.z*w.w;
            acc[3][0]+=a.w*w.x; acc[3][1]+=a.w*w.y; acc[3][2]+=a.w*w.z; acc[3][3]+=a.w*w.w;
        }
        __syncthreads();
    }
    #pragma unroll
    for (int i = 0; i < 4; ++i) {
        const int orow = n0 + r0 + i;
        if (orow < n)
            *(float4*)&out[(size_t)orow * COUT + c0] =
                make_float4(acc[i][0], acc[i][1], acc[i][2], acc[i][3]);
    }
}

static inline size_t align16(size_t x) { return (x + 15) & ~(size_t)15; }

extern "C" void kernel_launch(void* const* d_in, const int* in_sizes, int n_in,
                              void* d_out, int out_size, void* d_ws, size_t ws_size,
                              hipStream_t stream) {
    const float*         feat = (const float*)d_in[0];
    const int*           nmap = (const int*)d_in[1];
    const unsigned char* m8   = (const unsigned char*)d_in[2];
    const int*           m32  = (const int*)d_in[2];
    const float*         wk   = (const float*)d_in[3];
    float*               out  = (float*)d_out;

    const int n = in_sizes[0] / CIN;
    int* flag = (int*)d_ws;
    float* zrow = (float*)((char*)d_ws + 64);       // 64B zero row

    const size_t feat_off   = 128;
    const size_t feat_bytes = (size_t)n * CIN * 2;
    const size_t midx_off   = align16(feat_off + feat_bytes);
    const size_t midx_bytes = (size_t)K_OFF * n * 4;
    const size_t wt2_off    = align16(midx_off + midx_bytes);
    const size_t wt2_bytes  = (size_t)K_OFF * 4 * 64 * 8 * 2;
    const size_t needed     = wt2_off + wt2_bytes;

    const int mask_elems = K_OFF * n;
    const int det_bytes  = mask_elems < 4096 ? mask_elems : 4096;
    detect_mask<<<1, 256, 0, stream>>>(m8, det_bytes, flag, zrow);

    if (ws_size >= needed) {
        unsigned short* featb = (unsigned short*)((char*)d_ws + feat_off);
        int*            midx  = (int*)((char*)d_ws + midx_off);
        unsigned short* wt2   = (unsigned short*)((char*)d_ws + wt2_off);
        const int Bf = (n * CIN / 8 + 255) / 256;
        const int Bm = ((K_OFF * n + 3) / 4 + 255) / 256;
        const int Bw = (K_OFF * 4 * 64 + 255) / 256;
        prep_kernel<<<Bf + Bm + Bw, 256, 0, stream>>>(
            feat, nmap, m8, m32, wk, featb, midx, wt2, n, Bf, Bm, flag);
        const int nblocks = (n + 127) / 128;
        conv_mfma10<<<nblocks, 256, 0, stream>>>(
            featb, midx, wt2, (const unsigned short*)zrow, out, n);
    } else {
        const int nb = (n + BN - 1) / BN;
        sparse_conv_fp32<<<nb, 256, 0, stream>>>(feat, nmap, m8, m32, wk, out, n, flag);
    }
}